// Round 7
// baseline (334.519 us; speedup 1.0000x reference)
//
#include <hip/hip_runtime.h>
#include <stdint.h>

#define B_ 2
#define S_ 2048
#define HID_ 2048
#define H_ 16
#define D_ 128
#define LOG2E 1.44269504088896f

typedef __bf16 bf16;
typedef __bf16 bf16x8 __attribute__((ext_vector_type(8)));
typedef __bf16 bf16x4 __attribute__((ext_vector_type(4)));
typedef float floatx4 __attribute__((ext_vector_type(4)));

#define MFMA16(a, b, c) __builtin_amdgcn_mfma_f32_16x16x32_bf16(a, b, c, 0, 0, 0)

__device__ __forceinline__ void gload_lds16(const bf16* g, bf16* l) {
  __builtin_amdgcn_global_load_lds(
      (const __attribute__((address_space(1))) uint32_t*)g,
      (__attribute__((address_space(3))) uint32_t*)l, 16, 0, 0);
}

// ---------------- unified prep kernel ----------------
// Round-7 rework (round-6 cooperative mega-kernel silently no-opped -> reverted
// to the verified 4-dispatch structure):
//  * pack_a: reads were an 8KB-stride row-gather (16 L2 lines per load instr).
//    Now: coalesced row-major float4 reads -> LDS [128][36] f32 tile -> emit
//    fragments from LDS (same scheme pack_b already used).
//  * both packs: store order l = sub + 32*i (dense 512B wave stores; the old
//    l = sub*2+i left 16B holes per instruction).
__device__ __forceinline__ void pack_a_body(const float* __restrict__ in,
                                            bf16* __restrict__ out,
                                            int K, int nk, int mb, int kb,
                                            float (*ft)[36]) {
  int t = threadIdx.x;
  // read phase: fully coalesced (8 lanes x 16B = one 128B line per row)
#pragma unroll
  for (int p = 0; p < 4; p++) {
    int row = p * 32 + (t >> 3);
    int col4 = (t & 7) * 4;
    float4 v = *(const float4*)(in + (size_t)(mb * 128 + row) * K + kb * 32 + col4);
    *(float4*)&ft[row][col4] = v;
  }
  __syncthreads();
  // emit phase: fragments from LDS, dense 16B stores
  int c = t >> 5, sub = t & 31;
  bf16* obase = out + (((size_t)mb * nk + kb) * 8 + c) * 512;
#pragma unroll
  for (int i = 0; i < 2; i++) {
    int l = sub + 32 * i;
    int rowl = c * 16 + (l & 15);
    int colb = (l >> 4) * 8;
    bf16x8 o;
#pragma unroll
    for (int j = 0; j < 8; j++) o[j] = (bf16)ft[rowl][colb + j];
    *(bf16x8*)(obase + l * 8) = o;
  }
}

__device__ __forceinline__ void pack_b_body(const float* __restrict__ W,
                                            bf16* __restrict__ out,
                                            int N, int nk, int nb, int kb,
                                            float (*ftile)[132]) {
  int t = threadIdx.x;
#pragma unroll
  for (int p = 0; p < 4; p++) {
    int row = p * 8 + (t >> 5);
    int col = (t & 31) * 4;
    float4 v = *(const float4*)(W + (size_t)(kb * 32 + row) * N + nb * 128 + col);
    *(float4*)&ftile[row][col] = v;
  }
  __syncthreads();
  int c = t >> 5, sub = t & 31;
  bf16* obase = out + (((size_t)nb * nk + kb) * 8 + c) * 512;
#pragma unroll
  for (int i = 0; i < 2; i++) {
    int l = sub + 32 * i;  // dense stores (was sub*2+i: 16B holes)
    int rbase = (l >> 4) * 8;
    int coln = c * 16 + (l & 15);
    bf16x8 o;
#pragma unroll
    for (int j = 0; j < 8; j++) o[j] = (bf16)ftile[rbase + j][coln];
    *(bf16x8*)(obase + l * 8) = o;
  }
}

//   blocks [0,256):        rotlut  (4096*16 entries)
//   blocks [256,2304):     pack_a  hidden (32 x 64 tile grid)
//   blocks [2304,5376):    pack_b  Wqkv   (48 x 64)
//   blocks [5376,6400):    pack_b  Wdense (16 x 64)
__global__ __launch_bounds__(256) void prep_k(const float* __restrict__ hidden,
                                              const float* __restrict__ Wqkv,
                                              const float* __restrict__ Wdense,
                                              const int* __restrict__ pos_ids,
                                              bf16* __restrict__ Ap1,
                                              bf16* __restrict__ Bp1,
                                              bf16* __restrict__ Bp2,
                                              float4* __restrict__ lut) {
  __shared__ __align__(16) char psm[128 * 36 * 4];  // 18 KB, shared by both tile shapes
  int bid = blockIdx.x;
  if (bid < 256) {
    int idx = bid * 256 + threadIdx.x;  // idx = row*16 + i
    int row = idx >> 4, i = idx & 15;
    float tp = (float)pos_ids[row];
    float invf = powf(10000.f, -(float)i * (1.f / 16.f));
    float fr = tp * invf;
    float cs = cosf(fr), sn = sinf(fr);
    float scl = ((float)(2 * i) + 12.8f) * (1.f / 44.8f);
    float sc = powf(scl, (tp - 1024.f) * (1.f / 512.f));
    float4 o;
    o.x = cs * sc;
    o.y = sn * sc;
    o.z = cs / sc;
    o.w = sn / sc;
    lut[idx] = o;
  } else if (bid < 2304) {
    int v = bid - 256;
    pack_a_body(hidden, Ap1, 2048, 64, v & 31, v >> 5, (float(*)[36])psm);
  } else if (bid < 5376) {
    int v = bid - 2304;
    pack_b_body(Wqkv, Bp1, 6144, 64, v % 48, v / 48, (float(*)[132])psm);
  } else {
    int v = bid - 5376;
    pack_b_body(Wdense, Bp2, 2048, 64, v & 15, v >> 4, (float(*)[132])psm);
  }
}

// ---------------- GEMM on packed operands: dbuf LDS, 1 barrier/iter ----------------
template <typename OutT>
__global__ __launch_bounds__(256, 2) void gemm_p_k(const bf16* __restrict__ Ap,
                                                   const bf16* __restrict__ Bp,
                                                   OutT* __restrict__ C,
                                                   int N, int nk) {
  __shared__ __align__(16) bf16 stage[2][8192];
  const int t = threadIdx.x;
  const int w = t >> 6, l = t & 63;
  const int quad = l >> 4, ln = l & 15;
  const int wm = w >> 1, wn = w & 1;
  const int mb = blockIdx.x, nb = blockIdx.y;

  const bf16* sbase = (w < 2 ? Ap + ((size_t)mb * nk * 8 + w * 4) * 512
                             : Bp + ((size_t)nb * nk * 8 + (w - 2) * 4) * 512) + l * 8;
  bf16* dbase0 = stage[0] + w * 2048;
  bf16* dbase1 = stage[1] + w * 2048;

  floatx4 acc[4][4] = {};

#pragma unroll
  for (int i = 0; i < 4; i++) gload_lds16(sbase + i * 512, dbase0 + i * 512);

  for (int kb = 0; kb < nk; kb++) {
    __syncthreads();
    if (kb + 1 < nk) {
      const bf16* s = sbase + (size_t)(kb + 1) * 4096;
      bf16* d = ((kb + 1) & 1) ? dbase1 : dbase0;
#pragma unroll
      for (int i = 0; i < 4; i++) gload_lds16(s + i * 512, d + i * 512);
    }
    const bf16* cur = stage[kb & 1];
    bf16x8 af[4], bfr[4];
#pragma unroll
    for (int mt = 0; mt < 4; mt++)
      af[mt] = *(const bf16x8*)(cur + (wm * 4 + mt) * 512 + l * 8);
#pragma unroll
    for (int nt = 0; nt < 4; nt++)
      bfr[nt] = *(const bf16x8*)(cur + 4096 + (wn * 4 + nt) * 512 + l * 8);
#pragma unroll
    for (int mt = 0; mt < 4; mt++)
#pragma unroll
      for (int nt = 0; nt < 4; nt++)
        acc[mt][nt] = MFMA16(af[mt], bfr[nt], acc[mt][nt]);
  }

  const int m0 = mb * 128, n0 = nb * 128;
#pragma unroll
  for (int mt = 0; mt < 4; mt++)
#pragma unroll
    for (int nt = 0; nt < 4; nt++) {
      int row = m0 + wm * 64 + mt * 16 + quad * 4;
      int col = n0 + wn * 64 + nt * 16 + ln;
      OutT* cp = C + (size_t)row * N + col;
#pragma unroll
      for (int r = 0; r < 4; r++)
        cp[(size_t)r * N] = (OutT)acc[mt][nt][r];
    }
}

// ---------------- fused QKV GEMM: rotary (via LUT) + scale + Q/Kp/Vp scatter ----------
__global__ __launch_bounds__(256, 2) void gemm_qkv_k(const bf16* __restrict__ Ap,
                                                     const bf16* __restrict__ Bp,
                                                     const float4* __restrict__ lut,
                                                     bf16* __restrict__ Q,
                                                     bf16* __restrict__ Kp,
                                                     bf16* __restrict__ Vp,
                                                     int nk) {
  __shared__ __align__(16) bf16 stage[2][8192];
  const int t = threadIdx.x;
  const int w = t >> 6, l = t & 63;
  const int quad = l >> 4, ln = l & 15;
  const int wm = w >> 1, wn = w & 1;
  const int mb = blockIdx.x, nb = blockIdx.y;

  const bf16* sbase = (w < 2 ? Ap + ((size_t)mb * nk * 8 + w * 4) * 512
                             : Bp + ((size_t)nb * nk * 8 + (w - 2) * 4) * 512) + l * 8;
  bf16* dbase0 = stage[0] + w * 2048;
  bf16* dbase1 = stage[1] + w * 2048;

  floatx4 acc[4][4] = {};

#pragma unroll
  for (int i = 0; i < 4; i++) gload_lds16(sbase + i * 512, dbase0 + i * 512);

  for (int kb = 0; kb < nk; kb++) {
    __syncthreads();
    if (kb + 1 < nk) {
      const bf16* s = sbase + (size_t)(kb + 1) * 4096;
      bf16* d = ((kb + 1) & 1) ? dbase1 : dbase0;
#pragma unroll
      for (int i = 0; i < 4; i++) gload_lds16(s + i * 512, d + i * 512);
    }
    const bf16* cur = stage[kb & 1];
    bf16x8 af[4], bfr[4];
#pragma unroll
    for (int mt = 0; mt < 4; mt++)
      af[mt] = *(const bf16x8*)(cur + (wm * 4 + mt) * 512 + l * 8);
#pragma unroll
    for (int nt = 0; nt < 4; nt++)
      bfr[nt] = *(const bf16x8*)(cur + 4096 + (wn * 4 + nt) * 512 + l * 8);
#pragma unroll
    for (int mt = 0; mt < 4; mt++)
#pragma unroll
      for (int nt = 0; nt < 4; nt++)
        acc[mt][nt] = MFMA16(af[mt], bfr[nt], acc[mt][nt]);
  }

  // ---- epilogue: acc[mt][nt][r] at row = mb*128+wm*64+mt*16+quad*4+r,
  //      d = wn*64 + nt*16 + ln
  const int h = nb / 3;
  const int type = nb - h * 3;
  const int m0 = mb * 128;

  if (type == 2) {
#pragma unroll
    for (int mt = 0; mt < 4; mt++) {
      int row0 = m0 + wm * 64 + mt * 16 + quad * 4;
      int b = row0 >> 11, s0 = row0 & 2047;
      size_t vb = (size_t)(b * 16 + h) * (S_ * D_) + (size_t)(s0 >> 6) * 8192;
      int lf = ((mt & 1) * 2 + (quad >> 1)) * 16 + ln;
      int j0 = (quad & 1) * 4;
#pragma unroll
      for (int nt = 0; nt < 4; nt++) {
        int cv = (wn * 4 + nt) * 2 + (mt >> 1);
        bf16x4 ov;
#pragma unroll
        for (int r = 0; r < 4; r++) ov[r] = (bf16)acc[mt][nt][r];
        *(bf16x4*)(Vp + vb + cv * 512 + lf * 8 + j0) = ov;
      }
    }
    return;
  }

  if (wn == 0) {  // rotary covers dims 0..31 = (nt=0, nt=1) pairs; wave-uniform
#pragma unroll
    for (int mt = 0; mt < 4; mt++)
#pragma unroll
      for (int r = 0; r < 4; r++) {
        int row = m0 + wm * 64 + mt * 16 + quad * 4 + r;
        float4 cf = lut[row * 16 + ln];
        float c_ = (type == 0) ? cf.x : cf.z;
        float s_ = (type == 0) ? cf.y : cf.w;
        float x1 = acc[mt][0][r], x2 = acc[mt][1][r];
        acc[mt][0][r] = x1 * c_ - x2 * s_;
        acc[mt][1][r] = x2 * c_ + x1 * s_;
      }
  }

  if (type == 0) {
    const float QS = 0.08838834764831845f * LOG2E;
#pragma unroll
    for (int mt = 0; mt < 4; mt++) {
      int row0 = m0 + wm * 64 + mt * 16 + quad * 4;
      int b = row0 >> 11, s0 = row0 & 2047;
      bf16* qb = Q + ((size_t)(b * 16 + h) * S_ + s0) * D_ + wn * 64 + ln;
#pragma unroll
      for (int nt = 0; nt < 4; nt++)
#pragma unroll
        for (int r = 0; r < 4; r++)
          qb[(size_t)r * D_ + nt * 16] = (bf16)(acc[mt][nt][r] * QS);
    }
  } else {
#pragma unroll
    for (int mt = 0; mt < 4; mt++) {
      int row0 = m0 + wm * 64 + mt * 16 + quad * 4;
      int b = row0 >> 11, s0 = row0 & 2047;
      bf16* kb_ = Kp + (size_t)(b * 16 + h) * (S_ * D_) + (size_t)(s0 >> 6) * 8192 + (ln & 7);
#pragma unroll
      for (int nt = 0; nt < 4; nt++) {
        int ck = mt * 4 + wn * 2 + (nt >> 1);
        int lp = ((nt & 1) * 2 + (ln >> 3)) * 16 + quad * 4;
#pragma unroll
        for (int r = 0; r < 4; r++)
          kb_[ck * 512 + (lp + r) * 8] = (bf16)acc[mt][nt][r];
      }
    }
  }
}

// ---------------- flash attention: lockstep waves + dbuf DMA; packed-A output ----------------
__global__ __launch_bounds__(256, 2) void flash_k(const bf16* __restrict__ Q,
                                                  const bf16* __restrict__ Kp,
                                                  const bf16* __restrict__ Vp,
                                                  const float* __restrict__ amask,
                                                  bf16* __restrict__ Ap2) {
  __shared__ __align__(16) bf16 stage[2][16384];
  __shared__ __align__(16) bf16 pbuf[4][16 * 72];
  int blk = blockIdx.x;
  int bh = blk & 31;
  int ab = blk >> 5;
  int b = bh >> 4, h = bh & 15;
  int t = threadIdx.x;
  int w = t >> 6, l = t & 63;
  int quad = l >> 4, ln = l & 15;

  const bf16* Kpb = Kp + (size_t)bh * (S_ * D_);
  const bf16* Vpb = Vp + (size_t)bh * (S_ * D_);
  const float* mbase = amask + (size_t)b * S_;
  bf16* pw = pbuf[w];

#pragma unroll
  for (int j = 0; j < 8; j++) {
    int gi = w * 8 + j;
    const bf16* src = (gi < 16 ? Kpb + gi * 512 : Vpb + (gi - 16) * 512) + l * 8;
    gload_lds16(src, stage[0] + gi * 512);
  }

  int it = 0;
#pragma unroll 1
  for (int phase = 0; phase < 2; phase++) {
    int a = phase ? (31 - ab) : ab;
    int strip = a * 4 + w;
    int qs = strip * 16;
    int T = a + 1;

    const bf16* Qp = Q + (size_t)(bh * S_ + qs + ln) * D_;
    bf16x8 qf[4];
#pragma unroll
    for (int ks = 0; ks < 4; ks++)
      qf[ks] = *(const bf16x8*)(Qp + ks * 32 + quad * 8);

    floatx4 oacc[8] = {};
    float m_i = -1e30f, l_i = 0.f;

#pragma unroll 1
    for (int kt = 0; kt < T; kt++, it++) {
      __syncthreads();
      const bf16* cur = stage[it & 1];
      if (it != 32) {
        int nkv = (kt + 1 < T) ? (kt + 1) : 0;
        bf16* nb = stage[(it + 1) & 1];
#pragma unroll
        for (int j = 0; j < 8; j++) {
          int gi = w * 8 + j;
          const bf16* src = (gi < 16 ? Kpb + (size_t)nkv * 8192 + gi * 512
                                     : Vpb + (size_t)nkv * 8192 + (gi - 16) * 512) + l * 8;
          gload_lds16(src, nb + gi * 512);
        }
      }
      int kv0 = kt * 64;

      // mask loads first: latency hides under the QK MFMA cluster
      floatx4 am4[4];
#pragma unroll
      for (int mt = 0; mt < 4; mt++)
        am4[mt] = *(const floatx4*)(mbase + kv0 + mt * 16 + quad * 4);

      floatx4 acc[4] = {};
#pragma unroll
      for (int ks = 0; ks < 4; ks++)
#pragma unroll
        for (int mt = 0; mt < 4; mt++) {
          bf16x8 kf = *(const bf16x8*)(cur + (mt * 4 + ks) * 512 + l * 8);
          acc[mt] = MFMA16(kf, qf[ks], acc[mt]);
        }

      float v[4][4];
      float mx = -3.0e38f;
      if (kt == T - 1) {  // diag tile: causal mask (block-uniform branch)
        int q = qs + ln;
#pragma unroll
        for (int mt = 0; mt < 4; mt++)
#pragma unroll
          for (int r = 0; r < 4; r++) {
            float x = acc[mt][r] + am4[mt][r] * LOG2E;
            if (kv0 + mt * 16 + quad * 4 + r > q) x = -3.0e38f;
            v[mt][r] = x;
            mx = fmaxf(mx, x);
          }
      } else {
#pragma unroll
        for (int mt = 0; mt < 4; mt++)
#pragma unroll
          for (int r = 0; r < 4; r++) {
            float x = acc[mt][r] + am4[mt][r] * LOG2E;
            v[mt][r] = x;
            mx = fmaxf(mx, x);
          }
      }
      mx = fmaxf(mx, __shfl_xor(mx, 16, 64));
      mx = fmaxf(mx, __shfl_xor(mx, 32, 64));
      // T13 defer-max: only rescale when some row's max grew by > 8 (log2).
      if (__any(mx > m_i + 8.0f)) {
        float mnew = fmaxf(m_i, mx);
        float alpha = exp2f(m_i - mnew);
        l_i *= alpha;
#pragma unroll
        for (int dt = 0; dt < 8; dt++) oacc[dt] *= alpha;
        m_i = mnew;
      }
      float sum = 0.f;
      bf16x4 pk[4];
#pragma unroll
      for (int mt = 0; mt < 4; mt++)
#pragma unroll
        for (int r = 0; r < 4; r++) {
          float p = exp2f(v[mt][r] - m_i);
          sum += p;
          pk[mt][r] = (bf16)p;
        }
      sum += __shfl_xor(sum, 16, 64);
      sum += __shfl_xor(sum, 32, 64);
      l_i += sum;

#pragma unroll
      for (int mt = 0; mt < 4; mt++)
        *(bf16x4*)(pw + ln * 72 + mt * 16 + quad * 4) = pk[mt];

      const bf16* vcur = cur + 8192;
#pragma unroll
      for (int ks = 0; ks < 2; ks++) {
        bf16x8 pf = *(const bf16x8*)(pw + ln * 72 + ks * 32 + quad * 8);
#pragma unroll
        for (int dt = 0; dt < 8; dt++) {
          bf16x8 vf = *(const bf16x8*)(vcur + (dt * 2 + ks) * 512 + l * 8);
          oacc[dt] = MFMA16(vf, pf, oacc[dt]);
        }
      }
    }

    // epilogue: normalize + store in gemm2's packed-A layout
    float inv_l = 1.0f / l_i;
    int mrow = b * S_ + qs;  // multiple of 16
    int mb2 = mrow >> 7;
    int cc = (mrow >> 4) & 7;
    bf16* abase = Ap2 + ((size_t)mb2 * 64 * 8 + cc) * 512;
#pragma unroll
    for (int dt = 0; dt < 8; dt++) {
      bf16x4 ov;
#pragma unroll
      for (int r = 0; r < 4; r++) ov[r] = (bf16)(oacc[dt][r] * inv_l);
      int kb2 = h * 4 + (dt >> 1);
      int lp = ((dt & 1) * 2 + (quad >> 1)) * 16 + ln;
      *(bf16x4*)(abase + (size_t)kb2 * 4096 + lp * 8 + (quad & 1) * 4) = ov;
    }
  }
}

// ---------------- launch ----------------
extern "C" void kernel_launch(void* const* d_in, const int* in_sizes, int n_in,
                              void* d_out, int out_size, void* d_ws, size_t ws_size,
                              hipStream_t stream) {
  const float* hidden = (const float*)d_in[0];
  const float* amask = (const float*)d_in[1];
  const float* Wqkv = (const float*)d_in[2];
  const float* Wdense = (const float*)d_in[3];
  const int* posids = (const int*)d_in[4];
  float* out = (float*)d_out;
  char* ws = (char*)d_ws;

  // workspace layout (101.7 MB used; all live ranges disjoint):
  //  [0,        8.39M)  Bp2 (Wdense packed)       — lives until gemm2
  //  [8.39M,  25.17M)  Ap1 (hidden packed) -> Ap2 (attn packed, written by flash)
  //  [25.17M, 50.33M)  Bp1 (Wqkv packed)
  //  [50.33M, 67.11M)  Q
  //  [67.11M, 83.89M)  Kp
  //  [83.89M,100.66M)  Vp
  //  [100.66M,101.71M) rotary LUT (float4 x 4096 x 16)
  bf16* Bp2 = (bf16*)(ws + 0);
  bf16* Ap1 = (bf16*)(ws + 8388608ull);
  bf16* Ap2 = (bf16*)(ws + 8388608ull);
  bf16* Bp1 = (bf16*)(ws + 25165824ull);
  bf16* Qb = (bf16*)(ws + 50331648ull);
  bf16* Kpb = (bf16*)(ws + 67108864ull);
  bf16* Vpb = (bf16*)(ws + 83886080ull);
  float4* lut = (float4*)(ws + 100663296ull);

  prep_k<<<6400, 256, 0, stream>>>(hidden, Wqkv, Wdense, posids, Ap1, Bp1, Bp2, lut);
  gemm_qkv_k<<<dim3(32, 48), 256, 0, stream>>>(Ap1, Bp1, lut, Qb, Kpb, Vpb, 64);
  flash_k<<<512, 256, 0, stream>>>(Qb, Kpb, Vpb, amask, Ap2);
  gemm_p_k<float><<<dim3(32, 16), 256, 0, stream>>>(Ap2, Bp2, out, 2048, 64);
}